// Round 5
// baseline (378.172 us; speedup 1.0000x reference)
//
#include <hip/hip_runtime.h>

typedef __attribute__((ext_vector_type(4))) float f32x4;
typedef __attribute__((ext_vector_type(8))) short bf16x8;
typedef __attribute__((ext_vector_type(2))) unsigned int u32x2;
typedef unsigned short ushort_t;

#define L_DIM  256
#define H_IN_D 300
#define KP     320     // padded K for ALL stages (composed weights are 300-col)
#define BM     64
#define LDH    328     // h LDS row stride in ushorts (656 B) — aggregate-balanced for b128 reads
#define NTH    256

__device__ __forceinline__ ushort_t f2bf(float f) {
  unsigned u = __builtin_bit_cast(unsigned, f);
  unsigned r = u + 0x7fffu + ((u >> 16) & 1u);   // RNE, no NaN in data
  return (ushort_t)(r >> 16);
}
__device__ __forceinline__ unsigned pk2(float lo, float hi) {
  return (unsigned)f2bf(lo) | ((unsigned)f2bf(hi) << 16);
}

// ---------------- precompute kernels ----------------
// Mc_0 = W0 (256x300). Mb_0 = bf16(W0) zero-padded to 320 cols.
__global__ void cvt0(const float* __restrict__ W0, ushort_t* __restrict__ Mb0) {
  int i = blockIdx.x * blockDim.x + threadIdx.x;
  if (i >= 256 * KP) return;
  int n = i / KP, k = i - n * KP;
  Mb0[i] = (k < H_IN_D) ? f2bf(W0[n * H_IN_D + k]) : (ushort_t)0;
}

// Mc_s = Ws @ Mc_{s-1}  (256x300, f32);  c_s = Ws @ c_{s-1} + bs;  Mb_s = bf16(Mc_s) padded.
// One block per output row n.
__global__ __launch_bounds__(256) void comp(
    const float* __restrict__ Wmat,   // [256][256]
    const float* __restrict__ Min,    // [256][300] f32
    const float* __restrict__ bvec,   // [256]
    const float* __restrict__ cin,    // [256]
    float* __restrict__ Mout,         // [256][300] f32
    float* __restrict__ cout,         // [256]
    ushort_t* __restrict__ Mb)        // [256][320] bf16
{
  __shared__ float wrow[256];
  __shared__ float cbuf[256];
  __shared__ float red[4];
  const int n = blockIdx.x;
  const int tid = threadIdx.x;
  wrow[tid] = Wmat[n * 256 + tid];
  cbuf[tid] = cin[tid];
  __syncthreads();

  // c_out[n] = sum_j W[n][j] c_in[j] + b[n]  (block reduction)
  float cp = wrow[tid] * cbuf[tid];
  cp += __shfl_xor(cp, 1);  cp += __shfl_xor(cp, 2);  cp += __shfl_xor(cp, 4);
  cp += __shfl_xor(cp, 8);  cp += __shfl_xor(cp, 16); cp += __shfl_xor(cp, 32);
  if ((tid & 63) == 0) red[tid >> 6] = cp;

  // row n of Mout: k = tid (0..255) and k1 = 256+tid (tid<44)
  float a0 = 0.f, a1 = 0.f;
  const int k1 = 256 + tid;
#pragma unroll 8
  for (int j = 0; j < 256; ++j) {
    float w = wrow[j];
    a0 = fmaf(w, Min[j * H_IN_D + tid], a0);
    if (tid < 44) a1 = fmaf(w, Min[j * H_IN_D + k1], a1);
  }
  __syncthreads();
  if (tid == 0) cout[n] = red[0] + red[1] + red[2] + red[3] + bvec[n];

  Mout[n * H_IN_D + tid] = a0;
  Mb[n * KP + tid] = f2bf(a0);
  if (tid < 44) { Mout[n * H_IN_D + k1] = a1; Mb[n * KP + k1] = f2bf(a1); }
  if (tid >= 236) Mb[n * KP + (tid + 64)] = (ushort_t)0;   // pad k=300..319
}

// ---------------- fused flow kernel ----------------
// Block = 64 rows, 4 waves; wave owns 64 output cols (c0 = wave*64).
// All 4 stages: v_s = h @ Mc_s^T + c_s, K=320. acc layout (R3-verified):
//   acc[nt][mt][j] = v[m = mt*16 + r][n = c0 + nt*16 + g*4 + j]
// zr mirrors this layout so dot+update are register-local; per-row reduction:
// in-register over 16 cols -> shfl_xor(16,32) over g -> LDS partial over waves.
__global__ __launch_bounds__(NTH, 2) void flow_fused(
    const float* __restrict__ z, const float* __restrict__ h,
    const ushort_t* __restrict__ Mb, const float* __restrict__ b0,
    const float* __restrict__ cvecs, float* __restrict__ out)
{
  __shared__ __align__(16) ushort_t hl[BM * LDH];     // 41984 B
  __shared__ float pvz[2][4][64];                     // 2 KB (double-buffered)
  __shared__ float pvv[2][4][64];                     // 2 KB

  const int tid  = threadIdx.x;
  const int wave = tid >> 6;
  const int lane = tid & 63;
  const int r    = lane & 15;
  const int g    = lane >> 4;
  const int row0 = blockIdx.x * BM;
  const int c0   = wave * 64;

  // ---- stage h -> LDS bf16, K padded 300->320 ----
  for (int row = wave; row < BM; row += 4) {
    const float* hrow = h + (row0 + row) * H_IN_D;
    f32x4 m4 = *(const f32x4*)(hrow + 4 * lane);
    u32x2 pm; pm[0] = pk2(m4[0], m4[1]); pm[1] = pk2(m4[2], m4[3]);
    *(u32x2*)&hl[row * LDH + 4 * lane] = pm;
    if (lane < 16) {
      f32x4 t4 = {0.f, 0.f, 0.f, 0.f};
      if (lane < 11) t4 = *(const f32x4*)(hrow + 256 + 4 * lane);
      u32x2 pt; pt[0] = pk2(t4[0], t4[1]); pt[1] = pk2(t4[2], t4[3]);
      *(u32x2*)&hl[row * LDH + 256 + 4 * lane] = pt;
    }
  }

  // ---- z tile -> registers, layout-matched to acc ----
  f32x4 zr[4][4];   // [mt][nt]
#pragma unroll
  for (int mt = 0; mt < 4; ++mt)
#pragma unroll
    for (int nt = 0; nt < 4; ++nt)
      zr[mt][nt] = *(const f32x4*)(z + (row0 + mt * 16 + r) * L_DIM + c0 + nt * 16 + g * 4);

  __syncthreads();

  const ushort_t* yb = hl + r * LDH + g * 8;

#pragma unroll
  for (int s = 0; s < 4; ++s) {
    const ushort_t* W   = Mb + s * (256 * KP);
    const float*   bias = (s == 0) ? b0 : (cvecs + (s - 1) * 256);
    const int pb = s & 1;

    f32x4 acc[4][4];   // [nt][mt]
#pragma unroll
    for (int a = 0; a < 4; ++a)
#pragma unroll
      for (int b = 0; b < 4; ++b) { acc[a][b][0]=0.f; acc[a][b][1]=0.f; acc[a][b][2]=0.f; acc[a][b][3]=0.f; }

    const ushort_t* xb = W + (c0 + r) * KP + g * 8;
#pragma unroll
    for (int ks = 0; ks < 10; ++ks) {
      bf16x8 x[4];
#pragma unroll
      for (int nt = 0; nt < 4; ++nt) x[nt] = *(const bf16x8*)(xb + nt * 16 * KP + ks * 32);
      bf16x8 y[4];
#pragma unroll
      for (int mt = 0; mt < 4; ++mt) y[mt] = *(const bf16x8*)(yb + mt * 16 * LDH + ks * 32);
#pragma unroll
      for (int nt = 0; nt < 4; ++nt) {
        acc[nt][0] = __builtin_amdgcn_mfma_f32_16x16x32_bf16(x[nt], y[0], acc[nt][0], 0, 0, 0);
        acc[nt][1] = __builtin_amdgcn_mfma_f32_16x16x32_bf16(x[nt], y[1], acc[nt][1], 0, 0, 0);
        acc[nt][2] = __builtin_amdgcn_mfma_f32_16x16x32_bf16(x[nt], y[2], acc[nt][2], 0, 0, 0);
        acc[nt][3] = __builtin_amdgcn_mfma_f32_16x16x32_bf16(x[nt], y[3], acc[nt][3], 0, 0, 0);
      }
    }

    // ---- v = acc + bias; per-row partial dots (register-local) ----
    float vz[4] = {0.f, 0.f, 0.f, 0.f};
    float vv[4] = {0.f, 0.f, 0.f, 0.f};
#pragma unroll
    for (int nt = 0; nt < 4; ++nt) {
      f32x4 bv = *(const f32x4*)(bias + c0 + nt * 16 + g * 4);
#pragma unroll
      for (int mt = 0; mt < 4; ++mt) {
#pragma unroll
        for (int j = 0; j < 4; ++j) {
          float v = acc[nt][mt][j] + bv[j];
          acc[nt][mt][j] = v;
          vz[mt] = fmaf(v, zr[mt][nt][j], vz[mt]);
          vv[mt] = fmaf(v, v, vv[mt]);
        }
      }
    }
#pragma unroll
    for (int mt = 0; mt < 4; ++mt) {
      vz[mt] += __shfl_xor(vz[mt], 16); vz[mt] += __shfl_xor(vz[mt], 32);
      vv[mt] += __shfl_xor(vv[mt], 16); vv[mt] += __shfl_xor(vv[mt], 32);
    }
    if (lane < 16) {
#pragma unroll
      for (int mt = 0; mt < 4; ++mt) {
        pvz[pb][wave][mt * 16 + r] = vz[mt];
        pvv[pb][wave][mt * 16 + r] = vv[mt];
      }
    }
    __syncthreads();

    // ---- a = 2 vz/vv per row; z -= a v (register-local) ----
#pragma unroll
    for (int mt = 0; mt < 4; ++mt) {
      const int rw = mt * 16 + r;
      float sz = pvz[pb][0][rw] + pvz[pb][1][rw] + pvz[pb][2][rw] + pvz[pb][3][rw];
      float sv = pvv[pb][0][rw] + pvv[pb][1][rw] + pvv[pb][2][rw] + pvv[pb][3][rw];
      float a = 2.f * sz / sv;
#pragma unroll
      for (int nt = 0; nt < 4; ++nt)
#pragma unroll
        for (int j = 0; j < 4; ++j)
          zr[mt][nt][j] = fmaf(-a, acc[nt][mt][j], zr[mt][nt][j]);
    }
  }

  // ---- store z ----
#pragma unroll
  for (int mt = 0; mt < 4; ++mt)
#pragma unroll
    for (int nt = 0; nt < 4; ++nt)
      *(f32x4*)(out + (row0 + mt * 16 + r) * L_DIM + c0 + nt * 16 + g * 4) = zr[mt][nt];
}

extern "C" void kernel_launch(void* const* d_in, const int* in_sizes, int n_in,
                              void* d_out, int out_size, void* d_ws, size_t ws_size,
                              hipStream_t stream) {
  const float* z  = (const float*)d_in[0];
  const float* h  = (const float*)d_in[1];
  const float* W0 = (const float*)d_in[2];
  const float* b0 = (const float*)d_in[3];
  const float* Ws = (const float*)d_in[4];
  const float* bs = (const float*)d_in[5];
  float* out = (float*)d_out;

  // ws layout
  ushort_t* Mb  = (ushort_t*)d_ws;                        // [4][256][320] bf16 = 655360 B
  float*    Mc1 = (float*)((char*)d_ws + 655360);         // [256][300] f32
  float*    Mc2 = (float*)((char*)d_ws + 962560);
  float*    Mc3 = (float*)((char*)d_ws + 1269760);
  float*    cv  = (float*)((char*)d_ws + 1576960);        // c1,c2,c3 [3][256]

  hipLaunchKernelGGL(cvt0, dim3((256 * KP + 255) / 256), dim3(256), 0, stream, W0, Mb);
  hipLaunchKernelGGL(comp, dim3(256), dim3(256), 0, stream,
                     Ws,             W0,  bs,       b0,       Mc1, cv,       Mb + 1 * 256 * KP);
  hipLaunchKernelGGL(comp, dim3(256), dim3(256), 0, stream,
                     Ws + 65536,     Mc1, bs + 256, cv,       Mc2, cv + 256, Mb + 2 * 256 * KP);
  hipLaunchKernelGGL(comp, dim3(256), dim3(256), 0, stream,
                     Ws + 131072,    Mc2, bs + 512, cv + 256, Mc3, cv + 512, Mb + 3 * 256 * KP);
  hipLaunchKernelGGL(flow_fused, dim3(65536 / BM), dim3(NTH), 0, stream,
                     z, h, Mb, b0, cv, out);
}

// Round 6
// 336.846 us; speedup vs baseline: 1.1227x; 1.1227x over previous
//
#include <hip/hip_runtime.h>

typedef __attribute__((ext_vector_type(4))) float f32x4;
typedef __attribute__((ext_vector_type(8))) short bf16x8;
typedef __attribute__((ext_vector_type(2))) unsigned int u32x2;
typedef unsigned short ushort_t;

#define L_DIM  256
#define H_IN_D 300
#define KP     320     // padded K for ALL stages (composed weights are 300-col)
#define BM     64
#define LDH    328     // LDS h stride (fallback path only)
#define NTH    256

__device__ __forceinline__ ushort_t f2bf(float f) {
  unsigned u = __builtin_bit_cast(unsigned, f);
  unsigned r = u + 0x7fffu + ((u >> 16) & 1u);   // RNE, no NaN in data
  return (ushort_t)(r >> 16);
}
__device__ __forceinline__ unsigned pk2(float lo, float hi) {
  return (unsigned)f2bf(lo) | ((unsigned)f2bf(hi) << 16);
}

// ---------------- h f32 -> bf16 [65536][320] streaming conversion ----------------
__global__ void hcvt(const float* __restrict__ h, ushort_t* __restrict__ hb) {
  const int NQ = 65536 * 80;                       // quads of 4 cols
  int i0 = blockIdx.x * blockDim.x + threadIdx.x;
  int stride = gridDim.x * blockDim.x;
  for (int i = i0; i < NQ; i += stride) {
    int b = i / 80, k4 = i - b * 80;
    u32x2 p;
    if (k4 < 75) {
      f32x4 v = *(const f32x4*)(h + (size_t)b * H_IN_D + k4 * 4);
      p[0] = pk2(v[0], v[1]); p[1] = pk2(v[2], v[3]);
    } else { p[0] = 0u; p[1] = 0u; }               // pad cols 300..319 = 0
    *(u32x2*)&hb[(size_t)b * KP + k4 * 4] = p;
  }
}

// ---------------- Mc_0 = W0 -> bf16 padded ----------------
__global__ void cvt0(const float* __restrict__ W0, ushort_t* __restrict__ Mb0) {
  int i = blockIdx.x * blockDim.x + threadIdx.x;
  if (i >= 256 * KP) return;
  int n = i / KP, k = i - n * KP;
  Mb0[i] = (k < H_IN_D) ? f2bf(W0[n * H_IN_D + k]) : (ushort_t)0;
}

// ---------------- weight composition: Mc_s = Ws @ Mc_{s-1}, c_s = Ws c_{s-1} + bs ----
// Block = output row n. Reduction j split 4-way across threads (q), 5 k-chains
// per thread -> no serial latency chain; LDS combine.
__global__ __launch_bounds__(256) void comp(
    const float* __restrict__ Wmat,   // [256][256]
    const float* __restrict__ Min,    // [256][300] f32
    const float* __restrict__ bvec,   // [256]
    const float* __restrict__ cin,    // [256]
    float* __restrict__ Mout,         // [256][300] f32
    float* __restrict__ cout,         // [256]
    ushort_t* __restrict__ Mb)        // [256][320] bf16
{
  __shared__ float wrow[256];
  __shared__ float psum[4][304];
  __shared__ float red[4];
  const int n = blockIdx.x;
  const int tid = threadIdx.x;
  const int q = tid >> 6;            // j-chunk 0..3
  const int u = tid & 63;

  float w = Wmat[n * 256 + tid];
  wrow[tid] = w;
  float cp = w * cin[tid];
  cp += __shfl_xor(cp, 1);  cp += __shfl_xor(cp, 2);  cp += __shfl_xor(cp, 4);
  cp += __shfl_xor(cp, 8);  cp += __shfl_xor(cp, 16); cp += __shfl_xor(cp, 32);
  if ((tid & 63) == 0) red[tid >> 6] = cp;
  __syncthreads();

  float a0 = 0.f, a1 = 0.f, a2 = 0.f, a3 = 0.f, a4 = 0.f;
#pragma unroll 8
  for (int jj = 0; jj < 64; ++jj) {
    int j = q * 64 + jj;
    float wj = wrow[j];
    const float* row = Min + (size_t)j * H_IN_D;
    a0 = fmaf(wj, row[u], a0);
    a1 = fmaf(wj, row[u + 64], a1);
    a2 = fmaf(wj, row[u + 128], a2);
    a3 = fmaf(wj, row[u + 192], a3);
    if (u < 44) a4 = fmaf(wj, row[u + 256], a4);
  }
  psum[q][u] = a0; psum[q][u + 64] = a1; psum[q][u + 128] = a2; psum[q][u + 192] = a3;
  if (u < 44) psum[q][u + 256] = a4;
  __syncthreads();

  {
    float s0 = psum[0][tid] + psum[1][tid] + psum[2][tid] + psum[3][tid];
    Mout[(size_t)n * H_IN_D + tid] = s0;
    Mb[n * KP + tid] = f2bf(s0);
    if (tid < 44) {
      int k = tid + 256;
      float s1 = psum[0][k] + psum[1][k] + psum[2][k] + psum[3][k];
      Mout[(size_t)n * H_IN_D + k] = s1;
      Mb[n * KP + k] = f2bf(s1);
    }
    if (tid >= 236) Mb[n * KP + (tid + 64)] = (ushort_t)0;   // pad 300..319
  }
  if (tid == 0) cout[n] = red[0] + red[1] + red[2] + red[3] + bvec[n];
}

// ---------------- fused flow kernel ----------------
// Block = 64 rows, 4 waves; wave owns 64 output cols (c0 = wave*64).
// v_s = h @ Mc_s^T + c_s (K=320).  acc[nt][mt][j] = v[mt*16+r][c0+nt*16+g*4+j]
// zr mirrors acc layout; per-row reduce: regs -> shfl(16,32) -> LDS over waves.
template<bool USE_HB>
__global__ __launch_bounds__(NTH, 2) void flow_fused(
    const float* __restrict__ z, const float* __restrict__ h,
    const ushort_t* __restrict__ hb,
    const ushort_t* __restrict__ Mb, const float* __restrict__ b0,
    const float* __restrict__ cvecs, float* __restrict__ out)
{
  __shared__ float pvz[2][4][64];
  __shared__ float pvv[2][4][64];
  __shared__ __align__(16) ushort_t hl[USE_HB ? 8 : BM * LDH];

  const int tid  = threadIdx.x;
  const int wave = tid >> 6;
  const int lane = tid & 63;
  const int r    = lane & 15;
  const int g    = lane >> 4;
  const int row0 = blockIdx.x * BM;
  const int c0   = wave * 64;

  if constexpr (!USE_HB) {
    // fallback: stage h -> LDS bf16 (fixed trip count -> batched loads)
#pragma unroll
    for (int i = 0; i < 16; ++i) {
      int row = wave + 4 * i;
      const float* hrow = h + (size_t)(row0 + row) * H_IN_D;
      f32x4 m4 = *(const f32x4*)(hrow + 4 * lane);
      u32x2 pm; pm[0] = pk2(m4[0], m4[1]); pm[1] = pk2(m4[2], m4[3]);
      *(u32x2*)&hl[row * LDH + 4 * lane] = pm;
      if (lane < 16) {
        f32x4 t4 = {0.f, 0.f, 0.f, 0.f};
        if (lane < 11) t4 = *(const f32x4*)(hrow + 256 + 4 * lane);
        u32x2 pt; pt[0] = pk2(t4[0], t4[1]); pt[1] = pk2(t4[2], t4[3]);
        *(u32x2*)&hl[row * LDH + 256 + 4 * lane] = pt;
      }
    }
  }

  // ---- z tile -> registers, layout-matched to acc ----
  f32x4 zr[4][4];   // [mt][nt]
#pragma unroll
  for (int mt = 0; mt < 4; ++mt)
#pragma unroll
    for (int nt = 0; nt < 4; ++nt)
      zr[mt][nt] = *(const f32x4*)(z + (size_t)(row0 + mt * 16 + r) * L_DIM + c0 + nt * 16 + g * 4);

  if constexpr (!USE_HB) __syncthreads();

  const ushort_t* yb;
  int ystr;
  if constexpr (USE_HB) { yb = hb + (size_t)(row0 + r) * KP + g * 8; ystr = KP; }
  else                  { yb = hl + r * LDH + g * 8;                 ystr = LDH; }

#pragma unroll
  for (int s = 0; s < 4; ++s) {
    const ushort_t* W   = Mb + s * (256 * KP);
    const float*   bias = (s == 0) ? b0 : (cvecs + (s - 1) * 256);
    const int pb = s & 1;

    f32x4 acc[4][4];   // [nt][mt]
#pragma unroll
    for (int a = 0; a < 4; ++a)
#pragma unroll
      for (int b = 0; b < 4; ++b) { acc[a][b][0]=0.f; acc[a][b][1]=0.f; acc[a][b][2]=0.f; acc[a][b][3]=0.f; }

    const ushort_t* xb = W + (c0 + r) * KP + g * 8;
#pragma unroll
    for (int ks = 0; ks < 10; ++ks) {
      bf16x8 x[4];
#pragma unroll
      for (int nt = 0; nt < 4; ++nt) x[nt] = *(const bf16x8*)(xb + nt * 16 * KP + ks * 32);
      bf16x8 y[4];
#pragma unroll
      for (int mt = 0; mt < 4; ++mt) y[mt] = *(const bf16x8*)(yb + mt * 16 * ystr + ks * 32);
#pragma unroll
      for (int nt = 0; nt < 4; ++nt) {
        acc[nt][0] = __builtin_amdgcn_mfma_f32_16x16x32_bf16(x[nt], y[0], acc[nt][0], 0, 0, 0);
        acc[nt][1] = __builtin_amdgcn_mfma_f32_16x16x32_bf16(x[nt], y[1], acc[nt][1], 0, 0, 0);
        acc[nt][2] = __builtin_amdgcn_mfma_f32_16x16x32_bf16(x[nt], y[2], acc[nt][2], 0, 0, 0);
        acc[nt][3] = __builtin_amdgcn_mfma_f32_16x16x32_bf16(x[nt], y[3], acc[nt][3], 0, 0, 0);
      }
    }

    // ---- v = acc + bias; per-row partial dots (register-local) ----
    float vz[4] = {0.f, 0.f, 0.f, 0.f};
    float vv[4] = {0.f, 0.f, 0.f, 0.f};
#pragma unroll
    for (int nt = 0; nt < 4; ++nt) {
      f32x4 bv = *(const f32x4*)(bias + c0 + nt * 16 + g * 4);
#pragma unroll
      for (int mt = 0; mt < 4; ++mt) {
#pragma unroll
        for (int j = 0; j < 4; ++j) {
          float v = acc[nt][mt][j] + bv[j];
          acc[nt][mt][j] = v;
          vz[mt] = fmaf(v, zr[mt][nt][j], vz[mt]);
          vv[mt] = fmaf(v, v, vv[mt]);
        }
      }
    }
#pragma unroll
    for (int mt = 0; mt < 4; ++mt) {
      vz[mt] += __shfl_xor(vz[mt], 16); vz[mt] += __shfl_xor(vz[mt], 32);
      vv[mt] += __shfl_xor(vv[mt], 16); vv[mt] += __shfl_xor(vv[mt], 32);
    }
    if (lane < 16) {
#pragma unroll
      for (int mt = 0; mt < 4; ++mt) {
        pvz[pb][wave][mt * 16 + r] = vz[mt];
        pvv[pb][wave][mt * 16 + r] = vv[mt];
      }
    }
    __syncthreads();

    // ---- a = 2 vz/vv per row; z -= a v (register-local) ----
#pragma unroll
    for (int mt = 0; mt < 4; ++mt) {
      const int rw = mt * 16 + r;
      float sz = pvz[pb][0][rw] + pvz[pb][1][rw] + pvz[pb][2][rw] + pvz[pb][3][rw];
      float sv = pvv[pb][0][rw] + pvv[pb][1][rw] + pvv[pb][2][rw] + pvv[pb][3][rw];
      float a = 2.f * sz / sv;
#pragma unroll
      for (int nt = 0; nt < 4; ++nt)
#pragma unroll
        for (int j = 0; j < 4; ++j)
          zr[mt][nt][j] = fmaf(-a, acc[nt][mt][j], zr[mt][nt][j]);
    }
  }

  // ---- store z ----
#pragma unroll
  for (int mt = 0; mt < 4; ++mt)
#pragma unroll
    for (int nt = 0; nt < 4; ++nt)
      *(f32x4*)(out + (size_t)(row0 + mt * 16 + r) * L_DIM + c0 + nt * 16 + g * 4) = zr[mt][nt];
}

extern "C" void kernel_launch(void* const* d_in, const int* in_sizes, int n_in,
                              void* d_out, int out_size, void* d_ws, size_t ws_size,
                              hipStream_t stream) {
  const float* z  = (const float*)d_in[0];
  const float* h  = (const float*)d_in[1];
  const float* W0 = (const float*)d_in[2];
  const float* b0 = (const float*)d_in[3];
  const float* Ws = (const float*)d_in[4];
  const float* bs = (const float*)d_in[5];
  float* out = (float*)d_out;

  // ws layout
  ushort_t* Mb  = (ushort_t*)d_ws;                        // [4][256][320] bf16 = 655360 B
  float*    Mc1 = (float*)((char*)d_ws + 655360);         // [256][300] f32
  float*    Mc2 = (float*)((char*)d_ws + 962560);
  float*    Mc3 = (float*)((char*)d_ws + 1269760);
  float*    cv  = (float*)((char*)d_ws + 1576960);        // c1,c2,c3 [3][256]
  ushort_t* hb  = (ushort_t*)((char*)d_ws + 1581056);     // [65536][320] bf16 = 41943040 B
  const size_t need = 1581056 + (size_t)65536 * KP * 2;
  const bool use_hb = (ws_size >= need);

  if (use_hb)
    hipLaunchKernelGGL(hcvt, dim3(2048), dim3(256), 0, stream, h, hb);
  hipLaunchKernelGGL(cvt0, dim3((256 * KP + 255) / 256), dim3(256), 0, stream, W0, Mb);
  hipLaunchKernelGGL(comp, dim3(256), dim3(256), 0, stream,
                     Ws,          W0,  bs,       b0,       Mc1, cv,       Mb + 1 * 256 * KP);
  hipLaunchKernelGGL(comp, dim3(256), dim3(256), 0, stream,
                     Ws + 65536,  Mc1, bs + 256, cv,       Mc2, cv + 256, Mb + 2 * 256 * KP);
  hipLaunchKernelGGL(comp, dim3(256), dim3(256), 0, stream,
                     Ws + 131072, Mc2, bs + 512, cv + 256, Mc3, cv + 512, Mb + 3 * 256 * KP);
  if (use_hb)
    hipLaunchKernelGGL(flow_fused<true>, dim3(65536 / BM), dim3(NTH), 0, stream,
                       z, h, hb, Mb, b0, cv, out);
  else
    hipLaunchKernelGGL(flow_fused<false>, dim3(65536 / BM), dim3(NTH), 0, stream,
                       z, h, (const ushort_t*)nullptr, Mb, b0, cv, out);
}

// Round 7
// 219.881 us; speedup vs baseline: 1.7199x; 1.5320x over previous
//
#include <hip/hip_runtime.h>

typedef __attribute__((ext_vector_type(4))) float f32x4;
typedef __attribute__((ext_vector_type(8))) short bf16x8;
typedef __attribute__((ext_vector_type(2))) unsigned int u32x2;
typedef unsigned short ushort_t;

#define L_DIM  256
#define H_IN_D 300
#define KP     320     // padded K for ALL stages (composed weights are 300-col)
#define BM     64
#define LDH    328     // h LDS row stride in ushorts (656 B)
#define NTH    512     // 8 waves; wave owns 32 output cols

__device__ __forceinline__ ushort_t f2bf(float f) {
  unsigned u = __builtin_bit_cast(unsigned, f);
  unsigned r = u + 0x7fffu + ((u >> 16) & 1u);   // RNE, no NaN in data
  return (ushort_t)(r >> 16);
}
__device__ __forceinline__ unsigned pk2(float lo, float hi) {
  return (unsigned)f2bf(lo) | ((unsigned)f2bf(hi) << 16);
}

// ---------------- Mc_0 = W0 -> bf16 padded ----------------
__global__ void cvt0(const float* __restrict__ W0, ushort_t* __restrict__ Mb0) {
  int i = blockIdx.x * blockDim.x + threadIdx.x;
  if (i >= 256 * KP) return;
  int n = i / KP, k = i - n * KP;
  Mb0[i] = (k < H_IN_D) ? f2bf(W0[n * H_IN_D + k]) : (ushort_t)0;
}

// ---------------- weight composition: Mc_s = Ws @ Mc_{s-1}, c_s = Ws c_{s-1} + bs ----
__global__ __launch_bounds__(256) void comp(
    const float* __restrict__ Wmat,   // [256][256]
    const float* __restrict__ Min,    // [256][300] f32
    const float* __restrict__ bvec,   // [256]
    const float* __restrict__ cin,    // [256]
    float* __restrict__ Mout,         // [256][300] f32
    float* __restrict__ cout,         // [256]
    ushort_t* __restrict__ Mb)        // [256][320] bf16
{
  __shared__ float wrow[256];
  __shared__ float psum[4][304];
  __shared__ float red[4];
  const int n = blockIdx.x;
  const int tid = threadIdx.x;
  const int q = tid >> 6;
  const int u = tid & 63;

  float w = Wmat[n * 256 + tid];
  wrow[tid] = w;
  float cp = w * cin[tid];
  cp += __shfl_xor(cp, 1);  cp += __shfl_xor(cp, 2);  cp += __shfl_xor(cp, 4);
  cp += __shfl_xor(cp, 8);  cp += __shfl_xor(cp, 16); cp += __shfl_xor(cp, 32);
  if ((tid & 63) == 0) red[tid >> 6] = cp;
  __syncthreads();

  float a0 = 0.f, a1 = 0.f, a2 = 0.f, a3 = 0.f, a4 = 0.f;
#pragma unroll 8
  for (int jj = 0; jj < 64; ++jj) {
    int j = q * 64 + jj;
    float wj = wrow[j];
    const float* row = Min + (size_t)j * H_IN_D;
    a0 = fmaf(wj, row[u], a0);
    a1 = fmaf(wj, row[u + 64], a1);
    a2 = fmaf(wj, row[u + 128], a2);
    a3 = fmaf(wj, row[u + 192], a3);
    if (u < 44) a4 = fmaf(wj, row[u + 256], a4);
  }
  psum[q][u] = a0; psum[q][u + 64] = a1; psum[q][u + 128] = a2; psum[q][u + 192] = a3;
  if (u < 44) psum[q][u + 256] = a4;
  __syncthreads();

  {
    float s0 = psum[0][tid] + psum[1][tid] + psum[2][tid] + psum[3][tid];
    Mout[(size_t)n * H_IN_D + tid] = s0;
    Mb[n * KP + tid] = f2bf(s0);
    if (tid < 44) {
      int k = tid + 256;
      float s1 = psum[0][k] + psum[1][k] + psum[2][k] + psum[3][k];
      Mout[(size_t)n * H_IN_D + k] = s1;
      Mb[n * KP + k] = f2bf(s1);
    }
    if (tid >= 236) Mb[n * KP + (tid + 64)] = (ushort_t)0;
  }
  if (tid == 0) cout[n] = red[0] + red[1] + red[2] + red[3] + bvec[n];
}

// ---------------- fused flow kernel ----------------
// Block = 64 rows, 8 waves; wave owns 32 output cols (c0 = wave*32).
// v_s = h @ Mc_s^T + c_s (K=320).  acc[nt][mt][j] = v[mt*16+r][c0+nt*16+g*4+j]
// (nt<2, mt<4). zr mirrors acc layout; per-row reduce: regs -> shfl(16,32)
// -> LDS partials over 8 waves. One barrier per stage (double-buffered pv).
__global__ __launch_bounds__(NTH, 4) void flow_fused(
    const float* __restrict__ z, const float* __restrict__ h,
    const ushort_t* __restrict__ Mb, const float* __restrict__ b0,
    const float* __restrict__ cvecs, float* __restrict__ out)
{
  __shared__ __align__(16) ushort_t hl[BM * LDH];     // 41984 B
  __shared__ float pvz[2][8][64];                     // 2 KB x2 buf
  __shared__ float pvv[2][8][64];                     // 2 KB x2 buf

  const int tid  = threadIdx.x;
  const int wave = tid >> 6;         // 0..7
  const int lane = tid & 63;
  const int r    = lane & 15;
  const int g    = lane >> 4;        // 0..3
  const int row0 = blockIdx.x * BM;
  const int c0   = wave * 32;

  // ---- stage h -> LDS bf16, K padded 300->320 (fixed trip count) ----
#pragma unroll
  for (int i = 0; i < 8; ++i) {
    const int row = wave * 8 + i;
    const float* hrow = h + (size_t)(row0 + row) * H_IN_D;
    f32x4 m4 = *(const f32x4*)(hrow + 4 * lane);
    u32x2 pm; pm[0] = pk2(m4[0], m4[1]); pm[1] = pk2(m4[2], m4[3]);
    *(u32x2*)&hl[row * LDH + 4 * lane] = pm;
    if (lane < 16) {
      f32x4 t4 = {0.f, 0.f, 0.f, 0.f};
      if (lane < 11) t4 = *(const f32x4*)(hrow + 256 + 4 * lane);
      u32x2 pt; pt[0] = pk2(t4[0], t4[1]); pt[1] = pk2(t4[2], t4[3]);
      *(u32x2*)&hl[row * LDH + 256 + 4 * lane] = pt;
    }
  }

  // ---- z tile -> registers, layout-matched to acc ----
  f32x4 zr[4][2];   // [mt][nt]
#pragma unroll
  for (int mt = 0; mt < 4; ++mt)
#pragma unroll
    for (int nt = 0; nt < 2; ++nt)
      zr[mt][nt] = *(const f32x4*)(z + (size_t)(row0 + mt * 16 + r) * L_DIM + c0 + nt * 16 + g * 4);

  __syncthreads();

  const ushort_t* yb = hl + r * LDH + g * 8;

#pragma unroll
  for (int s = 0; s < 4; ++s) {
    const ushort_t* W   = Mb + s * (256 * KP);
    const float*   bias = (s == 0) ? b0 : (cvecs + (s - 1) * 256);
    const int pb = s & 1;

    f32x4 acc[2][4];   // [nt][mt]
#pragma unroll
    for (int a = 0; a < 2; ++a)
#pragma unroll
      for (int b = 0; b < 4; ++b) { acc[a][b][0]=0.f; acc[a][b][1]=0.f; acc[a][b][2]=0.f; acc[a][b][3]=0.f; }

    const ushort_t* xb = W + (c0 + r) * KP + g * 8;
#pragma unroll
    for (int ks = 0; ks < 10; ++ks) {
      bf16x8 x[2];
#pragma unroll
      for (int nt = 0; nt < 2; ++nt) x[nt] = *(const bf16x8*)(xb + nt * 16 * KP + ks * 32);
      bf16x8 y[4];
#pragma unroll
      for (int mt = 0; mt < 4; ++mt) y[mt] = *(const bf16x8*)(yb + mt * 16 * LDH + ks * 32);
#pragma unroll
      for (int nt = 0; nt < 2; ++nt) {
        acc[nt][0] = __builtin_amdgcn_mfma_f32_16x16x32_bf16(x[nt], y[0], acc[nt][0], 0, 0, 0);
        acc[nt][1] = __builtin_amdgcn_mfma_f32_16x16x32_bf16(x[nt], y[1], acc[nt][1], 0, 0, 0);
        acc[nt][2] = __builtin_amdgcn_mfma_f32_16x16x32_bf16(x[nt], y[2], acc[nt][2], 0, 0, 0);
        acc[nt][3] = __builtin_amdgcn_mfma_f32_16x16x32_bf16(x[nt], y[3], acc[nt][3], 0, 0, 0);
      }
    }

    // ---- v = acc + bias; per-row partial dots (register-local) ----
    float vz[4] = {0.f, 0.f, 0.f, 0.f};
    float vv[4] = {0.f, 0.f, 0.f, 0.f};
#pragma unroll
    for (int nt = 0; nt < 2; ++nt) {
      f32x4 bv = *(const f32x4*)(bias + c0 + nt * 16 + g * 4);
#pragma unroll
      for (int mt = 0; mt < 4; ++mt) {
#pragma unroll
        for (int j = 0; j < 4; ++j) {
          float v = acc[nt][mt][j] + bv[j];
          acc[nt][mt][j] = v;
          vz[mt] = fmaf(v, zr[mt][nt][j], vz[mt]);
          vv[mt] = fmaf(v, v, vv[mt]);
        }
      }
    }
#pragma unroll
    for (int mt = 0; mt < 4; ++mt) {
      vz[mt] += __shfl_xor(vz[mt], 16); vz[mt] += __shfl_xor(vz[mt], 32);
      vv[mt] += __shfl_xor(vv[mt], 16); vv[mt] += __shfl_xor(vv[mt], 32);
    }
    if (lane < 16) {
#pragma unroll
      for (int mt = 0; mt < 4; ++mt) {
        pvz[pb][wave][mt * 16 + r] = vz[mt];
        pvv[pb][wave][mt * 16 + r] = vv[mt];
      }
    }
    __syncthreads();

    // ---- a = 2 vz/vv per row; z -= a v (register-local) ----
#pragma unroll
    for (int mt = 0; mt < 4; ++mt) {
      const int rw = mt * 16 + r;
      float sz = 0.f, sv = 0.f;
#pragma unroll
      for (int w = 0; w < 8; ++w) { sz += pvz[pb][w][rw]; sv += pvv[pb][w][rw]; }
      float a = 2.f * sz / sv;
#pragma unroll
      for (int nt = 0; nt < 2; ++nt)
#pragma unroll
        for (int j = 0; j < 4; ++j)
          zr[mt][nt][j] = fmaf(-a, acc[nt][mt][j], zr[mt][nt][j]);
    }
  }

  // ---- store z ----
#pragma unroll
  for (int mt = 0; mt < 4; ++mt)
#pragma unroll
    for (int nt = 0; nt < 2; ++nt)
      *(f32x4*)(out + (size_t)(row0 + mt * 16 + r) * L_DIM + c0 + nt * 16 + g * 4) = zr[mt][nt];
}

extern "C" void kernel_launch(void* const* d_in, const int* in_sizes, int n_in,
                              void* d_out, int out_size, void* d_ws, size_t ws_size,
                              hipStream_t stream) {
  const float* z  = (const float*)d_in[0];
  const float* h  = (const float*)d_in[1];
  const float* W0 = (const float*)d_in[2];
  const float* b0 = (const float*)d_in[3];
  const float* Ws = (const float*)d_in[4];
  const float* bs = (const float*)d_in[5];
  float* out = (float*)d_out;

  // ws layout
  ushort_t* Mb  = (ushort_t*)d_ws;                        // [4][256][320] bf16 = 655360 B
  float*    Mc1 = (float*)((char*)d_ws + 655360);         // [256][300] f32
  float*    Mc2 = (float*)((char*)d_ws + 962560);
  float*    Mc3 = (float*)((char*)d_ws + 1269760);
  float*    cv  = (float*)((char*)d_ws + 1576960);        // c1,c2,c3 [3][256]

  hipLaunchKernelGGL(cvt0, dim3((256 * KP + 255) / 256), dim3(256), 0, stream, W0, Mb);
  hipLaunchKernelGGL(comp, dim3(256), dim3(256), 0, stream,
                     Ws,          W0,  bs,       b0,       Mc1, cv,       Mb + 1 * 256 * KP);
  hipLaunchKernelGGL(comp, dim3(256), dim3(256), 0, stream,
                     Ws + 65536,  Mc1, bs + 256, cv,       Mc2, cv + 256, Mb + 2 * 256 * KP);
  hipLaunchKernelGGL(comp, dim3(256), dim3(256), 0, stream,
                     Ws + 131072, Mc2, bs + 512, cv + 256, Mc3, cv + 512, Mb + 3 * 256 * KP);
  hipLaunchKernelGGL(flow_fused, dim3(65536 / BM), dim3(NTH), 0, stream,
                     z, h, Mb, b0, cv, out);
}

// Round 8
// 212.890 us; speedup vs baseline: 1.7764x; 1.0328x over previous
//
#include <hip/hip_runtime.h>

typedef __attribute__((ext_vector_type(4))) float f32x4;
typedef __attribute__((ext_vector_type(2))) float f32x2;
typedef __attribute__((ext_vector_type(8))) short bf16x8;
typedef __attribute__((ext_vector_type(2))) unsigned int u32x2;
typedef unsigned short ushort_t;

#define L_DIM  256
#define H_IN_D 300
#define KP     320     // padded K for ALL stages (composed weights are 300-col)
#define BM     64
#define LDH    328     // h LDS row stride in ushorts (656 B)
#define NTH    1024    // 16 waves; wave owns 16 output cols

__device__ __forceinline__ ushort_t f2bf(float f) {
  unsigned u = __builtin_bit_cast(unsigned, f);
  unsigned r = u + 0x7fffu + ((u >> 16) & 1u);   // RNE, no NaN in data
  return (ushort_t)(r >> 16);
}
__device__ __forceinline__ unsigned pk2(float lo, float hi) {
  return (unsigned)f2bf(lo) | ((unsigned)f2bf(hi) << 16);
}

// ---------------- Mc_0 = W0 -> bf16 padded ----------------
__global__ void cvt0(const float* __restrict__ W0, ushort_t* __restrict__ Mb0) {
  int i = blockIdx.x * blockDim.x + threadIdx.x;
  if (i >= 256 * KP) return;
  int n = i / KP, k = i - n * KP;
  Mb0[i] = (k < H_IN_D) ? f2bf(W0[n * H_IN_D + k]) : (ushort_t)0;
}

// ---------------- weight composition: Mc_s = Ws @ Mc_{s-1}, c_s = Ws c_{s-1} + bs ----
__global__ __launch_bounds__(256) void comp(
    const float* __restrict__ Wmat,   // [256][256]
    const float* __restrict__ Min,    // [256][300] f32
    const float* __restrict__ bvec,   // [256]
    const float* __restrict__ cin,    // [256]
    float* __restrict__ Mout,         // [256][300] f32
    float* __restrict__ cout,         // [256]
    ushort_t* __restrict__ Mb)        // [256][320] bf16
{
  __shared__ float wrow[256];
  __shared__ float psum[4][304];
  __shared__ float red[4];
  const int n = blockIdx.x;
  const int tid = threadIdx.x;
  const int q = tid >> 6;
  const int u = tid & 63;

  float w = Wmat[n * 256 + tid];
  wrow[tid] = w;
  float cp = w * cin[tid];
  cp += __shfl_xor(cp, 1);  cp += __shfl_xor(cp, 2);  cp += __shfl_xor(cp, 4);
  cp += __shfl_xor(cp, 8);  cp += __shfl_xor(cp, 16); cp += __shfl_xor(cp, 32);
  if ((tid & 63) == 0) red[tid >> 6] = cp;
  __syncthreads();

  float a0 = 0.f, a1 = 0.f, a2 = 0.f, a3 = 0.f, a4 = 0.f;
#pragma unroll 8
  for (int jj = 0; jj < 64; ++jj) {
    int j = q * 64 + jj;
    float wj = wrow[j];
    const float* row = Min + (size_t)j * H_IN_D;
    a0 = fmaf(wj, row[u], a0);
    a1 = fmaf(wj, row[u + 64], a1);
    a2 = fmaf(wj, row[u + 128], a2);
    a3 = fmaf(wj, row[u + 192], a3);
    if (u < 44) a4 = fmaf(wj, row[u + 256], a4);
  }
  psum[q][u] = a0; psum[q][u + 64] = a1; psum[q][u + 128] = a2; psum[q][u + 192] = a3;
  if (u < 44) psum[q][u + 256] = a4;
  __syncthreads();

  {
    float s0 = psum[0][tid] + psum[1][tid] + psum[2][tid] + psum[3][tid];
    Mout[(size_t)n * H_IN_D + tid] = s0;
    Mb[n * KP + tid] = f2bf(s0);
    if (tid < 44) {
      int k = tid + 256;
      float s1 = psum[0][k] + psum[1][k] + psum[2][k] + psum[3][k];
      Mout[(size_t)n * H_IN_D + k] = s1;
      Mb[n * KP + k] = f2bf(s1);
    }
    if (tid >= 236) Mb[n * KP + (tid + 64)] = (ushort_t)0;
  }
  if (tid == 0) cout[n] = red[0] + red[1] + red[2] + red[3] + bvec[n];
}

// ---------------- fused flow kernel ----------------
// Block = 64 rows, 16 waves; wave owns 16 output cols (c0 = wave*16).
// v_s = h @ Mc_s^T + c_s (K=320).  acc[mt][j] = v[mt*16+r][c0+g*4+j]
// zr mirrors acc layout. Per-row reduce: regs -> shfl(16,32) folds g ->
// float2 LDS partials over 16 waves (double-buffered, 1 barrier/stage).
__global__ __launch_bounds__(NTH, 4) void flow_fused(
    const float* __restrict__ z, const float* __restrict__ h,
    const ushort_t* __restrict__ Mb, const float* __restrict__ b0,
    const float* __restrict__ cvecs, float* __restrict__ out)
{
  __shared__ __align__(16) ushort_t hl[BM * LDH];   // 41984 B
  __shared__ f32x2 pvzv[2][16][64];                 // 16384 B

  const int tid  = threadIdx.x;
  const int wave = tid >> 6;         // 0..15
  const int lane = tid & 63;
  const int r    = lane & 15;
  const int g    = lane >> 4;        // 0..3
  const int row0 = blockIdx.x * BM;
  const int c0   = wave * 16;

  // ---- stage h -> LDS bf16, K padded 300->320 (4 rows per wave) ----
#pragma unroll
  for (int i = 0; i < 4; ++i) {
    const int row = wave * 4 + i;
    const float* hrow = h + (size_t)(row0 + row) * H_IN_D;
    f32x4 m4 = *(const f32x4*)(hrow + 4 * lane);
    u32x2 pm; pm[0] = pk2(m4[0], m4[1]); pm[1] = pk2(m4[2], m4[3]);
    *(u32x2*)&hl[row * LDH + 4 * lane] = pm;
    if (lane < 16) {
      f32x4 t4 = {0.f, 0.f, 0.f, 0.f};
      if (lane < 11) t4 = *(const f32x4*)(hrow + 256 + 4 * lane);
      u32x2 pt; pt[0] = pk2(t4[0], t4[1]); pt[1] = pk2(t4[2], t4[3]);
      *(u32x2*)&hl[row * LDH + 256 + 4 * lane] = pt;
    }
  }

  // ---- z tile -> registers, layout-matched to acc ----
  f32x4 zr[4];   // [mt]
#pragma unroll
  for (int mt = 0; mt < 4; ++mt)
    zr[mt] = *(const f32x4*)(z + (size_t)(row0 + mt * 16 + r) * L_DIM + c0 + g * 4);

  __syncthreads();

  const ushort_t* yb = hl + r * LDH + g * 8;

#pragma unroll
  for (int s = 0; s < 4; ++s) {
    const ushort_t* W   = Mb + s * (256 * KP);
    const float*   bias = (s == 0) ? b0 : (cvecs + (s - 1) * 256);
    const int pb = s & 1;

    f32x4 acc[4];   // [mt]
#pragma unroll
    for (int a = 0; a < 4; ++a) { acc[a][0]=0.f; acc[a][1]=0.f; acc[a][2]=0.f; acc[a][3]=0.f; }

    const ushort_t* xb = W + (c0 + r) * KP + g * 8;
#pragma unroll
    for (int ks = 0; ks < 10; ++ks) {
      bf16x8 x = *(const bf16x8*)(xb + ks * 32);
      bf16x8 y0 = *(const bf16x8*)(yb + 0 * 16 * LDH + ks * 32);
      bf16x8 y1 = *(const bf16x8*)(yb + 1 * 16 * LDH + ks * 32);
      bf16x8 y2 = *(const bf16x8*)(yb + 2 * 16 * LDH + ks * 32);
      bf16x8 y3 = *(const bf16x8*)(yb + 3 * 16 * LDH + ks * 32);
      acc[0] = __builtin_amdgcn_mfma_f32_16x16x32_bf16(x, y0, acc[0], 0, 0, 0);
      acc[1] = __builtin_amdgcn_mfma_f32_16x16x32_bf16(x, y1, acc[1], 0, 0, 0);
      acc[2] = __builtin_amdgcn_mfma_f32_16x16x32_bf16(x, y2, acc[2], 0, 0, 0);
      acc[3] = __builtin_amdgcn_mfma_f32_16x16x32_bf16(x, y3, acc[3], 0, 0, 0);
    }

    // ---- v = acc + bias; per-row partial dots (register-local) ----
    f32x4 bv = *(const f32x4*)(bias + c0 + g * 4);
    float vz[4], vv[4];
#pragma unroll
    for (int mt = 0; mt < 4; ++mt) {
      vz[mt] = 0.f; vv[mt] = 0.f;
#pragma unroll
      for (int j = 0; j < 4; ++j) {
        float v = acc[mt][j] + bv[j];
        acc[mt][j] = v;
        vz[mt] = fmaf(v, zr[mt][j], vz[mt]);
        vv[mt] = fmaf(v, v, vv[mt]);
      }
      vz[mt] += __shfl_xor(vz[mt], 16); vv[mt] += __shfl_xor(vv[mt], 16);
      vz[mt] += __shfl_xor(vz[mt], 32); vv[mt] += __shfl_xor(vv[mt], 32);
    }
    if (lane < 16) {
#pragma unroll
      for (int mt = 0; mt < 4; ++mt) {
        f32x2 p; p[0] = vz[mt]; p[1] = vv[mt];
        pvzv[pb][wave][mt * 16 + r] = p;
      }
    }
    __syncthreads();

    // ---- a = 2 vz/vv per row; z -= a v (register-local) ----
#pragma unroll
    for (int mt = 0; mt < 4; ++mt) {
      const int rw = mt * 16 + r;
      float sz = 0.f, sv = 0.f;
#pragma unroll
      for (int w = 0; w < 16; ++w) {
        f32x2 t = pvzv[pb][w][rw];
        sz += t[0]; sv += t[1];
      }
      float a = 2.f * sz / sv;
#pragma unroll
      for (int j = 0; j < 4; ++j)
        zr[mt][j] = fmaf(-a, acc[mt][j], zr[mt][j]);
    }
  }

  // ---- store z ----
#pragma unroll
  for (int mt = 0; mt < 4; ++mt)
    *(f32x4*)(out + (size_t)(row0 + mt * 16 + r) * L_DIM + c0 + g * 4) = zr[mt];
}

extern "C" void kernel_launch(void* const* d_in, const int* in_sizes, int n_in,
                              void* d_out, int out_size, void* d_ws, size_t ws_size,
                              hipStream_t stream) {
  const float* z  = (const float*)d_in[0];
  const float* h  = (const float*)d_in[1];
  const float* W0 = (const float*)d_in[2];
  const float* b0 = (const float*)d_in[3];
  const float* Ws = (const float*)d_in[4];
  const float* bs = (const float*)d_in[5];
  float* out = (float*)d_out;

  // ws layout
  ushort_t* Mb  = (ushort_t*)d_ws;                        // [4][256][320] bf16 = 655360 B
  float*    Mc1 = (float*)((char*)d_ws + 655360);         // [256][300] f32
  float*    Mc2 = (float*)((char*)d_ws + 962560);
  float*    Mc3 = (float*)((char*)d_ws + 1269760);
  float*    cv  = (float*)((char*)d_ws + 1576960);        // c1,c2,c3 [3][256]

  hipLaunchKernelGGL(cvt0, dim3((256 * KP + 255) / 256), dim3(256), 0, stream, W0, Mb);
  hipLaunchKernelGGL(comp, dim3(256), dim3(256), 0, stream,
                     Ws,          W0,  bs,       b0,       Mc1, cv,       Mb + 1 * 256 * KP);
  hipLaunchKernelGGL(comp, dim3(256), dim3(256), 0, stream,
                     Ws + 65536,  Mc1, bs + 256, cv,       Mc2, cv + 256, Mb + 2 * 256 * KP);
  hipLaunchKernelGGL(comp, dim3(256), dim3(256), 0, stream,
                     Ws + 131072, Mc2, bs + 512, cv + 256, Mc3, cv + 512, Mb + 3 * 256 * KP);
  hipLaunchKernelGGL(flow_fused, dim3(65536 / BM), dim3(NTH), 0, stream,
                     z, h, Mb, b0, cv, out);
}